// Round 7
// baseline (136.001 us; speedup 1.0000x reference)
//
#include <hip/hip_runtime.h>
#include <math.h>

#define EPS 1e-8f
#define LN_2PI 1.8378770664093453f

// single 32-lane butterfly sum-reduction
__device__ __forceinline__ float redsum32(float v) {
    #pragma unroll
    for (int off = 16; off >= 1; off >>= 1)
        v += __shfl_xor(v, off);
    return v;
}

// One block per output position n (392), 1024 threads: c = t&31, h = t>>5 (0..31).
// Per pixel j (9 per n) a thread handles the single m = h (in-pixel index).
// amdgpu_waves_per_eu(4,4): pin allocator to 4 waves/SIMD -> 128-VGPR budget,
// so the ~110-float live set stays in registers (R6's 64-VGPR spill fix).
__global__ __attribute__((amdgpu_flat_work_group_size(1024, 1024), amdgpu_waves_per_eu(4, 4)))
void convcaps_em_kernel(const float* __restrict__ x,
                        const float* __restrict__ w,
                        const float* __restrict__ bu,
                        const float* __restrict__ ba,
                        float* __restrict__ out)
{
    __shared__ __align__(16) float sbuf[9 * 544];      // 19584 B
    __shared__ __align__(16) float red[8][32][36];     // 36864 B  (total 56448 B)

    const int n = blockIdx.x;
    const int t = threadIdx.x;
    const int c = t & 31;
    const int h = t >> 5;     // 0..31  (in-pixel capsule index)
    const int wv = t >> 6;    // 0..15

    // ---- stage 9 source pixels (544 ch each), coalesced float4 ----
    for (int idx = t; idx < 9 * 136; idx += 1024) {
        const int s  = idx / 136;
        const int e4 = idx - s * 136;
        int cell = n * 9 + s;
        const int b  = cell / 441; cell -= b * 441;
        const int kh = cell / 147; cell -= kh * 147;
        const int kw = cell / 49;  cell -= kw * 49;
        const int i  = cell / 7;
        const int j  = cell - i * 7;
        const float4* src = reinterpret_cast<const float4*>(
            x + (size_t)(((b * 16 + 2 * i + kh) * 16) + 2 * j + kw) * 544);
        reinterpret_cast<float4*>(sbuf + s * 544)[e4] = src[e4];
    }
    __syncthreads();
    // activation slots in place: f = a / (a + EPS)
    if (t < 288) {
        float* ap = sbuf + (t >> 5) * 544 + 512 + (t & 31);
        const float a = *ap;
        *ap = a / (a + EPS);
    }
    __syncthreads();

    const float bu_c = bu[c];
    const float ba_c = ba[c];

    float iv[16], dd[16];     // 0.5/sigma^2 and -2*mu*iv
    float lapBase = 0.0f;     // log a_out - sumHalfLog - 8 ln2pi - sum(mu^2 iv)
    #pragma unroll
    for (int p = 0; p < 16; ++p) { iv[p] = 0.0f; dd[p] = 0.0f; }

    #pragma unroll
    for (int it = 0; it < 3; ++it) {
        float pS0 = 0.0f, pS1[16], pS2[16];
        #pragma unroll
        for (int p = 0; p < 16; ++p) { pS1[p] = 0.0f; pS2[p] = 0.0f; }

        #pragma unroll 1
        for (int j = 0; j < 9; ++j) {
            const float* xb = sbuf + j * 544;
            const float* xp = xb + h * 16;
            const float* wp = w + ((size_t)((j << 5) + h) * 32 + c) * 16;

            float xa[16], wf[16];
            #pragma unroll
            for (int q = 0; q < 4; ++q) {
                float4 tx = reinterpret_cast<const float4*>(xp)[q];
                float4 tw = reinterpret_cast<const float4*>(wp)[q];
                xa[4*q] = tx.x; xa[4*q+1] = tx.y; xa[4*q+2] = tx.z; xa[4*q+3] = tx.w;
                wf[4*q] = tw.x; wf[4*q+1] = tw.y; wf[4*q+2] = tw.z; wf[4*q+3] = tw.w;
            }
            float v[16];
            #pragma unroll
            for (int p = 0; p < 4; ++p) {
                #pragma unroll
                for (int r = 0; r < 4; ++r) {
                    v[p*4+r] = fmaf(xa[p*4+3], wf[12+r],
                               fmaf(xa[p*4+2], wf[8+r],
                               fmaf(xa[p*4+1], wf[4+r], xa[p*4+0] * wf[r])));
                }
            }
            const float f = xb[512 + h];

            float rho;
            if (it == 0) {
                rho = f * 0.03125f;                      // r = 1/32 uniform
            } else {
                // lap = lapBase - sum_p (iv*v + dd)*v  (mu^2 folded into lapBase)
                float sA = 0.0f, sB = 0.0f;
                #pragma unroll
                for (int p = 0; p < 16; p += 2) {
                    sA = fmaf(fmaf(iv[p],   v[p],   dd[p]),   v[p],   sA);
                    sB = fmaf(fmaf(iv[p+1], v[p+1], dd[p+1]), v[p+1], sB);
                }
                // no max-subtraction: exp argument well inside f32 range for this data
                const float e = __expf(lapBase - (sA + sB));
                const float z = redsum32(e);
                rho = e * __fdividef(f, z);              // sum_c softmax = 1
            }

            pS0 += rho;
            #pragma unroll
            for (int p = 0; p < 16; ++p) {
                const float rv = rho * v[p];
                pS1[p] += rv;
                pS2[p] = fmaf(rv, v[p], pS2[p]);
            }
        }

        // ---- reduce over 32 h-groups (16 waves), two-level ----
        pS0 += __shfl_xor(pS0, 32);
        #pragma unroll
        for (int p = 0; p < 16; ++p) {
            pS1[p] += __shfl_xor(pS1[p], 32);
            pS2[p] += __shfl_xor(pS2[p], 32);
        }
        // level 1: waves 8..15 publish
        if (wv >= 8 && (t & 32) == 0) {
            float* rp = &red[wv - 8][c][0];
            #pragma unroll
            for (int q = 0; q < 4; ++q) {
                reinterpret_cast<float4*>(rp)[q] =
                    make_float4(pS1[4*q], pS1[4*q+1], pS1[4*q+2], pS1[4*q+3]);
                reinterpret_cast<float4*>(rp + 16)[q] =
                    make_float4(pS2[4*q], pS2[4*q+1], pS2[4*q+2], pS2[4*q+3]);
            }
            rp[32] = pS0;
        }
        __syncthreads();
        // level 2: waves 0..7 fold and write back
        if (wv < 8 && (t & 32) == 0) {
            float* rp = &red[wv][c][0];
            #pragma unroll
            for (int q = 0; q < 4; ++q) {
                float4 t1 = reinterpret_cast<const float4*>(rp)[q];
                float4 t2 = reinterpret_cast<const float4*>(rp + 16)[q];
                reinterpret_cast<float4*>(rp)[q] =
                    make_float4(pS1[4*q] + t1.x, pS1[4*q+1] + t1.y,
                                pS1[4*q+2] + t1.z, pS1[4*q+3] + t1.w);
                reinterpret_cast<float4*>(rp + 16)[q] =
                    make_float4(pS2[4*q] + t2.x, pS2[4*q+1] + t2.y,
                                pS2[4*q+2] + t2.z, pS2[4*q+3] + t2.w);
            }
            rp[32] += pS0;
        }
        __syncthreads();
        // final: every thread sums the 8 rows for its c
        float S0 = 0.0f, S1[16], S2[16];
        #pragma unroll
        for (int p = 0; p < 16; ++p) { S1[p] = 0.0f; S2[p] = 0.0f; }
        #pragma unroll
        for (int kk = 0; kk < 8; ++kk) {
            const float* rp = &red[kk][c][0];
            #pragma unroll
            for (int q = 0; q < 4; ++q) {
                const float4 t1 = reinterpret_cast<const float4*>(rp)[q];
                const float4 t2 = reinterpret_cast<const float4*>(rp + 16)[q];
                S1[4*q]   += t1.x; S1[4*q+1] += t1.y; S1[4*q+2] += t1.z; S1[4*q+3] += t1.w;
                S2[4*q]   += t2.x; S2[4*q+1] += t2.y; S2[4*q+2] += t2.z; S2[4*q+3] += t2.w;
            }
            S0 += rp[32];
        }
        __syncthreads();   // red reused next iteration

        // ---- m-step closure (redundant per-thread; c-dependent only) ----
        const float inv = 1.0f / (S0 + EPS);
        float sumHalfLog = 0.0f;
        if (it < 2) {
            float Cq = 0.0f;
            #pragma unroll
            for (int p = 0; p < 16; ++p) {
                const float m_ = S1[p] * inv;
                const float sg = (S2[p] - 2.0f * m_ * S1[p] + m_ * m_ * S0) * inv + EPS;
                const float ivp = 0.5f / sg;
                iv[p] = ivp;
                dd[p] = -2.0f * m_ * ivp;
                Cq = fmaf(m_ * m_, ivp, Cq);
                sumHalfLog += 0.5f * __logf(sg);
            }
            const float cost = (16.0f * bu_c + sumHalfLog) * S0;
            const float itc = (it == 0) ? 5.0e-4f : 9.75e-4f;
            const float a_out_c = 1.0f / (1.0f + __expf(-(itc * (ba_c - cost))));
            lapBase = __logf(a_out_c) - sumHalfLog - 8.0f * LN_2PI - Cq;
        } else {
            float mu[16];
            #pragma unroll
            for (int p = 0; p < 16; ++p) {
                const float m_ = S1[p] * inv;
                const float sg = (S2[p] - 2.0f * m_ * S1[p] + m_ * m_ * S0) * inv + EPS;
                mu[p] = m_;
                sumHalfLog += 0.5f * __logf(sg);
            }
            const float cost = (16.0f * bu_c + sumHalfLog) * S0;
            const float a_out_c = 1.0f / (1.0f + __expf(-(1.42625e-3f * (ba_c - cost))));
            if (h == 0) {
                float* po = out + (size_t)n * 544 + c * 16;
                #pragma unroll
                for (int q = 0; q < 4; ++q) {
                    reinterpret_cast<float4*>(po)[q] =
                        make_float4(mu[4*q], mu[4*q+1], mu[4*q+2], mu[4*q+3]);
                }
                out[(size_t)n * 544 + 512 + c] = a_out_c;
            }
        }
    }
}

extern "C" void kernel_launch(void* const* d_in, const int* in_sizes, int n_in,
                              void* d_out, int out_size, void* d_ws, size_t ws_size,
                              hipStream_t stream) {
    const float* x  = (const float*)d_in[0];   // (8,16,16,544) f32
    const float* w  = (const float*)d_in[1];   // (1,288,32,4,4) f32
    const float* bu = (const float*)d_in[2];   // (32,) f32
    const float* ba = (const float*)d_in[3];   // (32,) f32
    float* out = (float*)d_out;                // (8,7,7,544) f32
    convcaps_em_kernel<<<392, 1024, 0, stream>>>(x, w, bu, ba, out);
}

// Round 14
// 87.761 us; speedup vs baseline: 1.5497x; 1.5497x over previous
//
#include <hip/hip_runtime.h>
#include <math.h>

#define EPS 1e-8f
#define LN_2PI 1.8378770664093453f

#define WS_HALF 827904   // 784 blocks * 1056 floats

// single 32-lane butterfly sum-reduction
__device__ __forceinline__ float redsum32(float v) {
    #pragma unroll
    for (int off = 16; off >= 1; off >>= 1)
        v += __shfl_xor(v, off);
    return v;
}

// stage the 9 source pixels (544 ch each) of position n into sbuf (coalesced float4)
__device__ __forceinline__ void stage_pixels(const float* __restrict__ x,
                                             float* sbuf, const int n, const int t) {
    for (int idx = t; idx < 9 * 136; idx += 256) {
        const int s  = idx / 136;
        const int e4 = idx - s * 136;
        int cell = n * 9 + s;
        const int b  = cell / 441; cell -= b * 441;
        const int kh = cell / 147; cell -= kh * 147;
        const int kw = cell / 49;  cell -= kw * 49;
        const int i  = cell / 7;
        const int j  = cell - i * 7;
        const float4* src = reinterpret_cast<const float4*>(
            x + (size_t)(((b * 16 + 2 * i + kh) * 16) + 2 * j + kw) * 544);
        reinterpret_cast<float4*>(sbuf + s * 544)[e4] = src[e4];
    }
}

// transform ALL 288 activation slots in place: f = a / (a + EPS)
// (256 threads -> strided loop; an `if (t<288)` misses pixel 8 — R13 bug)
__device__ __forceinline__ void transform_act(float* sbuf, const int t) {
    for (int idx = t; idx < 288; idx += 256) {
        float* ap = sbuf + (idx >> 5) * 544 + 512 + (idx & 31);
        const float a = *ap;
        *ap = a / (a + EPS);
    }
}

// v = x(4x4) @ W(4x4) for one m; xa/wf loaded as float4 quads
__device__ __forceinline__ void compute_v(const float* xp, const float* wp, float* v) {
    float xa[16], wf[16];
    #pragma unroll
    for (int q = 0; q < 4; ++q) {
        float4 tx = reinterpret_cast<const float4*>(xp)[q];
        float4 tw = reinterpret_cast<const float4*>(wp)[q];
        xa[4*q] = tx.x; xa[4*q+1] = tx.y; xa[4*q+2] = tx.z; xa[4*q+3] = tx.w;
        wf[4*q] = tw.x; wf[4*q+1] = tw.y; wf[4*q+2] = tw.z; wf[4*q+3] = tw.w;
    }
    #pragma unroll
    for (int p = 0; p < 4; ++p) {
        #pragma unroll
        for (int r = 0; r < 4; ++r) {
            v[p*4+r] = fmaf(xa[p*4+3], wf[12+r],
                       fmaf(xa[p*4+2], wf[8+r],
                       fmaf(xa[p*4+1], wf[4+r], xa[p*4+0] * wf[r])));
        }
    }
}

// fold g-pairs wave-internally, publish 4 wave-rows to red, then write the
// block-partial (1056 floats) to ws[bid]
__device__ __forceinline__ void publish_partial(float pS0, const float* pS1, const float* pS2,
                                                float red[4][32][36], float* __restrict__ wsb,
                                                const int t, const int c, const int wv) {
    float s0 = pS0 + __shfl_xor(pS0, 32);
    float s1[16], s2[16];
    #pragma unroll
    for (int p = 0; p < 16; ++p) {
        s1[p] = pS1[p] + __shfl_xor(pS1[p], 32);
        s2[p] = pS2[p] + __shfl_xor(pS2[p], 32);
    }
    if ((t & 32) == 0) {
        float* rp = &red[wv][c][0];
        #pragma unroll
        for (int q = 0; q < 4; ++q) {
            reinterpret_cast<float4*>(rp)[q] =
                make_float4(s1[4*q], s1[4*q+1], s1[4*q+2], s1[4*q+3]);
            reinterpret_cast<float4*>(rp + 16)[q] =
                make_float4(s2[4*q], s2[4*q+1], s2[4*q+2], s2[4*q+3]);
        }
        rp[32] = s0;
    }
    __syncthreads();
    const float* rf = &red[0][0][0];
    for (int idx = t; idx < 1056; idx += 256) {
        const int cc = idx / 33;
        const int comp = idx - cc * 33;
        wsb[idx] = rf[(0*32 + cc)*36 + comp] + rf[(1*32 + cc)*36 + comp]
                 + rf[(2*32 + cc)*36 + comp] + rf[(3*32 + cc)*36 + comp];
    }
}

// ---------- K1: iteration-0 partials (uniform r = 1/32) ----------
__global__ __launch_bounds__(256, 2)
void caps_it0(const float* __restrict__ x, const float* __restrict__ w,
              float* __restrict__ ws1)
{
    __shared__ __align__(16) float sbuf[9 * 544];
    __shared__ __align__(16) float red[4][32][36];
    const int bid = blockIdx.x;
    const int n = bid >> 1, s = bid & 1;
    const int t = threadIdx.x, c = t & 31, g = t >> 5, wv = t >> 6;

    stage_pixels(x, sbuf, n, t);
    __syncthreads();
    transform_act(sbuf, t);
    __syncthreads();

    float pS0 = 0.0f, pS1[16], pS2[16];
    #pragma unroll
    for (int p = 0; p < 16; ++p) { pS1[p] = 0.0f; pS2[p] = 0.0f; }

    const int hb = s * 8 + g;            // in-pixel base index
    #pragma unroll 1
    for (int k = 0; k < 18; ++k) {
        const int j  = k >> 1;
        const int mi = hb + ((k & 1) << 4);
        float v[16];
        compute_v(sbuf + j * 544 + mi * 16,
                  w + ((size_t)((j << 5) + mi) * 32 + c) * 16, v);
        const float rho = sbuf[j * 544 + 512 + mi] * 0.03125f;
        pS0 += rho;
        #pragma unroll
        for (int p = 0; p < 16; ++p) {
            const float rv = rho * v[p];
            pS1[p] += rv;
            pS2[p] = fmaf(rv, v[p], pS2[p]);
        }
    }
    publish_partial(pS0, pS1, pS2, red, ws1 + (size_t)bid * 1056, t, c, wv);
}

// ---------- K2/K3: m-step closure from ws_in, then e-step partials to ws_out ----------
__global__ __launch_bounds__(256, 2)
void caps_estep(const float* __restrict__ x, const float* __restrict__ w,
                const float* __restrict__ bu, const float* __restrict__ ba,
                const float* __restrict__ ws_in, float* __restrict__ ws_out,
                const float itc)
{
    __shared__ __align__(16) float sbuf[9 * 544];
    __shared__ __align__(16) float red[4][32][36];
    float* sred = &red[0][0][0];         // alias: consumed before red is written
    const int bid = blockIdx.x;
    const int n = bid >> 1, s = bid & 1;
    const int t = threadIdx.x, c = t & 31, g = t >> 5, wv = t >> 6;

    stage_pixels(x, sbuf, n, t);
    // combine the two halves' partials into LDS
    for (int idx = t; idx < 1056; idx += 256)
        sred[idx] = ws_in[(size_t)(n * 2) * 1056 + idx]
                  + ws_in[(size_t)(n * 2 + 1) * 1056 + idx];
    __syncthreads();
    transform_act(sbuf, t);
    __syncthreads();

    // per-thread m-step closure for this c
    const float* Sc = sred + c * 33;
    const float S0 = Sc[32];
    const float inv = 1.0f / (S0 + EPS);
    float iv[16], dd[16];
    float Cq = 0.0f, shl = 0.0f;
    #pragma unroll
    for (int p = 0; p < 16; ++p) {
        const float S1p = Sc[p], S2p = Sc[16 + p];
        const float m_ = S1p * inv;
        const float sg = (S2p - 2.0f * m_ * S1p + m_ * m_ * S0) * inv + EPS;
        const float ivp = 0.5f / sg;
        iv[p] = ivp;
        dd[p] = -2.0f * m_ * ivp;
        Cq = fmaf(m_ * m_, ivp, Cq);
        shl += 0.5f * __logf(sg);
    }
    const float cost = (16.0f * bu[c] + shl) * S0;
    const float a_out = 1.0f / (1.0f + __expf(-(itc * (ba[c] - cost))));
    const float lapBase = __logf(a_out) - shl - 8.0f * LN_2PI - Cq;
    __syncthreads();                     // sred fully consumed before red reuse

    float pS0 = 0.0f, pS1[16], pS2[16];
    #pragma unroll
    for (int p = 0; p < 16; ++p) { pS1[p] = 0.0f; pS2[p] = 0.0f; }

    const int hb = s * 8 + g;
    #pragma unroll 1
    for (int k = 0; k < 18; ++k) {
        const int j  = k >> 1;
        const int mi = hb + ((k & 1) << 4);
        float v[16];
        compute_v(sbuf + j * 544 + mi * 16,
                  w + ((size_t)((j << 5) + mi) * 32 + c) * 16, v);
        const float f = sbuf[j * 544 + 512 + mi];

        // lap = lapBase - sum_p (iv*v + dd)*v  (mu^2 term folded into lapBase)
        float sA = 0.0f, sB = 0.0f;
        #pragma unroll
        for (int p = 0; p < 16; p += 2) {
            sA = fmaf(fmaf(iv[p],   v[p],   dd[p]),   v[p],   sA);
            sB = fmaf(fmaf(iv[p+1], v[p+1], dd[p+1]), v[p+1], sB);
        }
        const float e = __expf(lapBase - (sA + sB));   // no max-sub: range safe
        const float z = redsum32(e);
        const float rho = e * __fdividef(f, z);        // sum_c softmax = 1

        pS0 += rho;
        #pragma unroll
        for (int p = 0; p < 16; ++p) {
            const float rv = rho * v[p];
            pS1[p] += rv;
            pS2[p] = fmaf(rv, v[p], pS2[p]);
        }
    }
    publish_partial(pS0, pS1, pS2, red, ws_out + (size_t)bid * 1056, t, c, wv);
}

// ---------- K4: final m-step closure -> output ----------
__global__ __launch_bounds__(256)
void caps_final(const float* __restrict__ ws_in,
                const float* __restrict__ bu, const float* __restrict__ ba,
                float* __restrict__ out)
{
    const int t = threadIdx.x;
    const int n = blockIdx.x * 8 + (t >> 5);   // 49 blocks * 8 = 392
    const int c = t & 31;
    const float* A = ws_in + (size_t)(n * 2) * 1056 + c * 33;
    const float* B = ws_in + (size_t)(n * 2 + 1) * 1056 + c * 33;

    const float S0 = A[32] + B[32];
    const float inv = 1.0f / (S0 + EPS);
    float mu[16], shl = 0.0f;
    #pragma unroll
    for (int p = 0; p < 16; ++p) {
        const float S1p = A[p] + B[p];
        const float S2p = A[16 + p] + B[16 + p];
        const float m_ = S1p * inv;
        const float sg = (S2p - 2.0f * m_ * S1p + m_ * m_ * S0) * inv + EPS;
        mu[p] = m_;
        shl += 0.5f * __logf(sg);
    }
    const float cost = (16.0f * bu[c] + shl) * S0;
    const float a_out = 1.0f / (1.0f + __expf(-(1.42625e-3f * (ba[c] - cost))));

    float* po = out + (size_t)n * 544 + c * 16;
    #pragma unroll
    for (int q = 0; q < 4; ++q) {
        reinterpret_cast<float4*>(po)[q] =
            make_float4(mu[4*q], mu[4*q+1], mu[4*q+2], mu[4*q+3]);
    }
    out[(size_t)n * 544 + 512 + c] = a_out;
}

extern "C" void kernel_launch(void* const* d_in, const int* in_sizes, int n_in,
                              void* d_out, int out_size, void* d_ws, size_t ws_size,
                              hipStream_t stream) {
    const float* x  = (const float*)d_in[0];   // (8,16,16,544) f32
    const float* w  = (const float*)d_in[1];   // (1,288,32,4,4) f32
    const float* bu = (const float*)d_in[2];   // (32,) f32
    const float* ba = (const float*)d_in[3];   // (32,) f32
    float* out = (float*)d_out;                // (8,7,7,544) f32
    float* ws1 = (float*)d_ws;
    float* ws2 = ws1 + WS_HALF;

    caps_it0  <<<784, 256, 0, stream>>>(x, w, ws1);
    caps_estep<<<784, 256, 0, stream>>>(x, w, bu, ba, ws1, ws2, 5.0e-4f);
    caps_estep<<<784, 256, 0, stream>>>(x, w, bu, ba, ws2, ws1, 9.75e-4f);
    caps_final<<<49, 256, 0, stream>>>(ws1, bu, ba, out);
}

// Round 15
// 86.486 us; speedup vs baseline: 1.5725x; 1.0147x over previous
//
#include <hip/hip_runtime.h>
#include <hip/hip_cooperative_groups.h>
#include <math.h>

namespace cg = cooperative_groups;

#define EPS 1e-8f
#define LN_2PI 1.8378770664093453f

#define NBLK 784
#define WS_STRIDE 1056
#define WS_BUF (NBLK * WS_STRIDE)   // 827904 floats per ws buffer

// single 32-lane butterfly sum-reduction
__device__ __forceinline__ float redsum32(float v) {
    #pragma unroll
    for (int off = 16; off >= 1; off >>= 1)
        v += __shfl_xor(v, off);
    return v;
}

// stage the 9 source pixels (544 ch each) of position n into sbuf (coalesced float4)
__device__ __forceinline__ void stage_pixels(const float* __restrict__ x,
                                             float* sbuf, const int n, const int t) {
    for (int idx = t; idx < 9 * 136; idx += 256) {
        const int s  = idx / 136;
        const int e4 = idx - s * 136;
        int cell = n * 9 + s;
        const int b  = cell / 441; cell -= b * 441;
        const int kh = cell / 147; cell -= kh * 147;
        const int kw = cell / 49;  cell -= kw * 49;
        const int i  = cell / 7;
        const int j  = cell - i * 7;
        const float4* src = reinterpret_cast<const float4*>(
            x + (size_t)(((b * 16 + 2 * i + kh) * 16) + 2 * j + kw) * 544);
        reinterpret_cast<float4*>(sbuf + s * 544)[e4] = src[e4];
    }
}

// transform ALL 288 activation slots in place: f = a / (a + EPS)  (strided! R13 bug)
__device__ __forceinline__ void transform_act(float* sbuf, const int t) {
    for (int idx = t; idx < 288; idx += 256) {
        float* ap = sbuf + (idx >> 5) * 544 + 512 + (idx & 31);
        const float a = *ap;
        *ap = a / (a + EPS);
    }
}

// v = x(4x4) @ W(4x4) for one m
__device__ __forceinline__ void compute_v(const float* xp, const float* wp, float* v) {
    float xa[16], wf[16];
    #pragma unroll
    for (int q = 0; q < 4; ++q) {
        float4 tx = reinterpret_cast<const float4*>(xp)[q];
        float4 tw = reinterpret_cast<const float4*>(wp)[q];
        xa[4*q] = tx.x; xa[4*q+1] = tx.y; xa[4*q+2] = tx.z; xa[4*q+3] = tx.w;
        wf[4*q] = tw.x; wf[4*q+1] = tw.y; wf[4*q+2] = tw.z; wf[4*q+3] = tw.w;
    }
    #pragma unroll
    for (int p = 0; p < 4; ++p) {
        #pragma unroll
        for (int r = 0; r < 4; ++r) {
            v[p*4+r] = fmaf(xa[p*4+3], wf[12+r],
                       fmaf(xa[p*4+2], wf[8+r],
                       fmaf(xa[p*4+1], wf[4+r], xa[p*4+0] * wf[r])));
        }
    }
}

// fold g-pairs wave-internally, publish 4 wave-rows to red, write block-partial to ws[bid]
__device__ __forceinline__ void publish_partial(float pS0, const float* pS1, const float* pS2,
                                                float red[4][32][36], float* __restrict__ wsb,
                                                const int t, const int c, const int wv) {
    float s0 = pS0 + __shfl_xor(pS0, 32);
    float s1[16], s2[16];
    #pragma unroll
    for (int p = 0; p < 16; ++p) {
        s1[p] = pS1[p] + __shfl_xor(pS1[p], 32);
        s2[p] = pS2[p] + __shfl_xor(pS2[p], 32);
    }
    if ((t & 32) == 0) {
        float* rp = &red[wv][c][0];
        #pragma unroll
        for (int q = 0; q < 4; ++q) {
            reinterpret_cast<float4*>(rp)[q] =
                make_float4(s1[4*q], s1[4*q+1], s1[4*q+2], s1[4*q+3]);
            reinterpret_cast<float4*>(rp + 16)[q] =
                make_float4(s2[4*q], s2[4*q+1], s2[4*q+2], s2[4*q+3]);
        }
        rp[32] = s0;
    }
    __syncthreads();
    const float* rf = &red[0][0][0];
    for (int idx = t; idx < 1056; idx += 256) {
        const int cc = idx / 33;
        const int comp = idx - cc * 33;
        wsb[idx] = rf[(0*32 + cc)*36 + comp] + rf[(1*32 + cc)*36 + comp]
                 + rf[(2*32 + cc)*36 + comp] + rf[(3*32 + cc)*36 + comp];
    }
}

// it0 partial accumulation (uniform r = 1/32) over this block's 18 m's
__device__ __forceinline__ void it0_phase(const float* sbuf, float red[4][32][36],
                                          const float* __restrict__ w, float* __restrict__ wsb,
                                          const int s, const int t, const int c,
                                          const int g, const int wv) {
    float pS0 = 0.0f, pS1[16], pS2[16];
    #pragma unroll
    for (int p = 0; p < 16; ++p) { pS1[p] = 0.0f; pS2[p] = 0.0f; }
    const int hb = s * 8 + g;
    #pragma unroll 1
    for (int k = 0; k < 18; ++k) {
        const int j  = k >> 1;
        const int mi = hb + ((k & 1) << 4);
        float v[16];
        compute_v(sbuf + j * 544 + mi * 16,
                  w + ((size_t)((j << 5) + mi) * 32 + c) * 16, v);
        const float rho = sbuf[j * 544 + 512 + mi] * 0.03125f;
        pS0 += rho;
        #pragma unroll
        for (int p = 0; p < 16; ++p) {
            const float rv = rho * v[p];
            pS1[p] += rv;
            pS2[p] = fmaf(rv, v[p], pS2[p]);
        }
    }
    publish_partial(pS0, pS1, pS2, red, wsb, t, c, wv);
}

// m-step closure from ws_in (both halves of n), then e-step partials to ws_out
__device__ __forceinline__ void estep_phase(const float* sbuf, float red[4][32][36],
                                            const float* __restrict__ w,
                                            const float* __restrict__ bu,
                                            const float* __restrict__ ba,
                                            const float* __restrict__ ws_in,
                                            float* __restrict__ ws_out, const float itc,
                                            const int n, const int s, const int t,
                                            const int c, const int g, const int wv) {
    float* sred = &red[0][0][0];         // alias: consumed before red is rewritten
    for (int idx = t; idx < 1056; idx += 256)
        sred[idx] = ws_in[(size_t)(n * 2) * WS_STRIDE + idx]
                  + ws_in[(size_t)(n * 2 + 1) * WS_STRIDE + idx];
    __syncthreads();

    const float* Sc = sred + c * 33;
    const float S0 = Sc[32];
    const float inv = 1.0f / (S0 + EPS);
    float iv[16], dd[16];
    float Cq = 0.0f, shl = 0.0f;
    #pragma unroll
    for (int p = 0; p < 16; ++p) {
        const float S1p = Sc[p], S2p = Sc[16 + p];
        const float m_ = S1p * inv;
        const float sg = (S2p - 2.0f * m_ * S1p + m_ * m_ * S0) * inv + EPS;
        const float ivp = 0.5f / sg;
        iv[p] = ivp;
        dd[p] = -2.0f * m_ * ivp;
        Cq = fmaf(m_ * m_, ivp, Cq);
        shl += 0.5f * __logf(sg);
    }
    const float cost = (16.0f * bu[c] + shl) * S0;
    const float a_out = 1.0f / (1.0f + __expf(-(itc * (ba[c] - cost))));
    const float lapBase = __logf(a_out) - shl - 8.0f * LN_2PI - Cq;
    __syncthreads();                     // sred fully consumed before red reuse

    float pS0 = 0.0f, pS1[16], pS2[16];
    #pragma unroll
    for (int p = 0; p < 16; ++p) { pS1[p] = 0.0f; pS2[p] = 0.0f; }
    const int hb = s * 8 + g;
    #pragma unroll 1
    for (int k = 0; k < 18; ++k) {
        const int j  = k >> 1;
        const int mi = hb + ((k & 1) << 4);
        float v[16];
        compute_v(sbuf + j * 544 + mi * 16,
                  w + ((size_t)((j << 5) + mi) * 32 + c) * 16, v);
        const float f = sbuf[j * 544 + 512 + mi];
        float sA = 0.0f, sB = 0.0f;
        #pragma unroll
        for (int p = 0; p < 16; p += 2) {
            sA = fmaf(fmaf(iv[p],   v[p],   dd[p]),   v[p],   sA);
            sB = fmaf(fmaf(iv[p+1], v[p+1], dd[p+1]), v[p+1], sB);
        }
        const float e = __expf(lapBase - (sA + sB));   // no max-sub: range safe
        const float z = redsum32(e);
        const float rho = e * __fdividef(f, z);        // sum_c softmax = 1
        pS0 += rho;
        #pragma unroll
        for (int p = 0; p < 16; ++p) {
            const float rv = rho * v[p];
            pS1[p] += rv;
            pS2[p] = fmaf(rv, v[p], pS2[p]);
        }
    }
    publish_partial(pS0, pS1, pS2, red, ws_out, t, c, wv);
}

// final closure -> out (called by s==0 blocks)
__device__ __forceinline__ void final_phase(const float* __restrict__ ws_in,
                                            const float* __restrict__ bu,
                                            const float* __restrict__ ba,
                                            float* __restrict__ out,
                                            const int n, const int c, const int g) {
    const float* A = ws_in + (size_t)(n * 2) * WS_STRIDE + c * 33;
    const float* B = ws_in + (size_t)(n * 2 + 1) * WS_STRIDE + c * 33;
    const float S0 = A[32] + B[32];
    const float inv = 1.0f / (S0 + EPS);
    float mu[16], shl = 0.0f;
    #pragma unroll
    for (int p = 0; p < 16; ++p) {
        const float S1p = A[p] + B[p];
        const float S2p = A[16 + p] + B[16 + p];
        const float m_ = S1p * inv;
        const float sg = (S2p - 2.0f * m_ * S1p + m_ * m_ * S0) * inv + EPS;
        mu[p] = m_;
        shl += 0.5f * __logf(sg);
    }
    const float cost = (16.0f * bu[c] + shl) * S0;
    const float a_out = 1.0f / (1.0f + __expf(-(1.42625e-3f * (ba[c] - cost))));
    if (g == 0) {
        float* po = out + (size_t)n * 544 + c * 16;
        #pragma unroll
        for (int q = 0; q < 4; ++q) {
            reinterpret_cast<float4*>(po)[q] =
                make_float4(mu[4*q], mu[4*q+1], mu[4*q+2], mu[4*q+3]);
        }
        out[(size_t)n * 544 + 512 + c] = a_out;
    }
}

// ---------- cooperative single-kernel path ----------
// 784 blocks (n = bid>>1, half s = bid&1), 256 threads, full EM in one launch.
// ws buffers are write-once-read-once per launch (cross-XCD coherence safe).
__global__ __launch_bounds__(256, 2)
void caps_coop(const float* __restrict__ x, const float* __restrict__ w,
               const float* __restrict__ bu, const float* __restrict__ ba,
               float* __restrict__ wsA, float* __restrict__ wsB,
               float* __restrict__ wsC, float* __restrict__ out)
{
    cg::grid_group grid = cg::this_grid();
    __shared__ __align__(16) float sbuf[9 * 544];
    __shared__ __align__(16) float red[4][32][36];

    const int bid = blockIdx.x;
    const int n = bid >> 1, s = bid & 1;
    const int t = threadIdx.x, c = t & 31, g = t >> 5, wv = t >> 6;

    stage_pixels(x, sbuf, n, t);
    __syncthreads();
    transform_act(sbuf, t);
    __syncthreads();

    it0_phase(sbuf, red, w, wsA + (size_t)bid * WS_STRIDE, s, t, c, g, wv);
    __threadfence();
    grid.sync();

    estep_phase(sbuf, red, w, bu, ba, wsA, wsB + (size_t)bid * WS_STRIDE,
                5.0e-4f, n, s, t, c, g, wv);
    __threadfence();
    grid.sync();

    estep_phase(sbuf, red, w, bu, ba, wsB, wsC + (size_t)bid * WS_STRIDE,
                9.75e-4f, n, s, t, c, g, wv);
    __threadfence();
    grid.sync();

    if (s == 0)
        final_phase(wsC, bu, ba, out, n, c, g);
}

// ---------- fallback chain path (R14, correctness-proven) ----------
__global__ __launch_bounds__(256, 2)
void caps_it0(const float* __restrict__ x, const float* __restrict__ w,
              float* __restrict__ ws1)
{
    __shared__ __align__(16) float sbuf[9 * 544];
    __shared__ __align__(16) float red[4][32][36];
    const int bid = blockIdx.x;
    const int n = bid >> 1, s = bid & 1;
    const int t = threadIdx.x, c = t & 31, g = t >> 5, wv = t >> 6;
    stage_pixels(x, sbuf, n, t);
    __syncthreads();
    transform_act(sbuf, t);
    __syncthreads();
    it0_phase(sbuf, red, w, ws1 + (size_t)bid * WS_STRIDE, s, t, c, g, wv);
}

__global__ __launch_bounds__(256, 2)
void caps_estep(const float* __restrict__ x, const float* __restrict__ w,
                const float* __restrict__ bu, const float* __restrict__ ba,
                const float* __restrict__ ws_in, float* __restrict__ ws_out,
                const float itc)
{
    __shared__ __align__(16) float sbuf[9 * 544];
    __shared__ __align__(16) float red[4][32][36];
    const int bid = blockIdx.x;
    const int n = bid >> 1, s = bid & 1;
    const int t = threadIdx.x, c = t & 31, g = t >> 5, wv = t >> 6;
    stage_pixels(x, sbuf, n, t);
    __syncthreads();
    transform_act(sbuf, t);
    __syncthreads();
    estep_phase(sbuf, red, w, bu, ba, ws_in, ws_out + (size_t)bid * WS_STRIDE,
                itc, n, s, t, c, g, wv);
}

__global__ __launch_bounds__(256)
void caps_final(const float* __restrict__ ws_in,
                const float* __restrict__ bu, const float* __restrict__ ba,
                float* __restrict__ out)
{
    const int t = threadIdx.x;
    const int n = blockIdx.x * 8 + (t >> 5);   // 49 blocks * 8 = 392
    const int c = t & 31;
    final_phase(ws_in, bu, ba, out, n, c, 0);  // g=0: every lane writes its c
}

extern "C" void kernel_launch(void* const* d_in, const int* in_sizes, int n_in,
                              void* d_out, int out_size, void* d_ws, size_t ws_size,
                              hipStream_t stream) {
    const float* x  = (const float*)d_in[0];   // (8,16,16,544) f32
    const float* w  = (const float*)d_in[1];   // (1,288,32,4,4) f32
    const float* bu = (const float*)d_in[2];   // (32,) f32
    const float* ba = (const float*)d_in[3];   // (32,) f32
    float* out = (float*)d_out;                // (8,7,7,544) f32
    float* wsA = (float*)d_ws;
    float* wsB = wsA + WS_BUF;
    float* wsC = wsB + WS_BUF;

    // host-side co-residency check (capture-safe: no stream ops)
    int dev = 0;
    hipGetDevice(&dev);
    hipDeviceProp_t prop;
    hipGetDeviceProperties(&prop, dev);
    int maxBlocksPerCU = 0;
    hipOccupancyMaxActiveBlocksPerMultiprocessor(&maxBlocksPerCU,
                                                 (const void*)caps_coop, 256, 0);
    const bool coop_ok = (maxBlocksPerCU * prop.multiProcessorCount >= NBLK) &&
                         prop.cooperativeLaunch;

    if (coop_ok) {
        void* args[] = {(void*)&x, (void*)&w, (void*)&bu, (void*)&ba,
                        (void*)&wsA, (void*)&wsB, (void*)&wsC, (void*)&out};
        hipLaunchCooperativeKernel((const void*)caps_coop, dim3(NBLK), dim3(256),
                                   args, 0, stream);
    } else {
        caps_it0  <<<NBLK, 256, 0, stream>>>(x, w, wsA);
        caps_estep<<<NBLK, 256, 0, stream>>>(x, w, bu, ba, wsA, wsB, 5.0e-4f);
        caps_estep<<<NBLK, 256, 0, stream>>>(x, w, bu, ba, wsB, wsC, 9.75e-4f);
        caps_final<<<49, 256, 0, stream>>>(wsC, bu, ba, out);
    }
}

// Round 16
// 75.596 us; speedup vs baseline: 1.7991x; 1.1441x over previous
//
#include <hip/hip_runtime.h>
#include <math.h>

#define EPS 1e-8f
#define LN_2PI 1.8378770664093453f

// 4 interleaved independent 32-lane butterfly sum-reductions (4x ILP on shuffle latency)
__device__ __forceinline__ void redsum4(float& a, float& b, float& c, float& d) {
    #pragma unroll
    for (int off = 16; off >= 1; off >>= 1) {
        float ta = __shfl_xor(a, off);
        float tb = __shfl_xor(b, off);
        float tc = __shfl_xor(c, off);
        float td = __shfl_xor(d, off);
        a += ta; b += tb; c += tc; d += td;
    }
}

// One block per output position n (392), 256 threads.
// t -> (c = t&31, g = t>>5 in [0,8)); per j (=pixel) the thread handles the
// quad m = 32j + g + 8u, u=0..3  ->  36 m's total, 9 inner iterations.
// Grid-limited occupancy (392 blocks / 256 CUs): 2nd launch-bounds arg = 1 so
// the allocator gets a 256-VGPR budget -> room to software-pipeline W loads
// across j-iterations (unroll 3), which (256,2)+unroll-1 forbade.
__global__ __launch_bounds__(256, 1)
void convcaps_em_kernel(const float* __restrict__ x,
                        const float* __restrict__ w,
                        const float* __restrict__ bu,
                        const float* __restrict__ ba,
                        float* __restrict__ out)
{
    __shared__ __align__(16) float sbuf[9 * 544];      // 19584 B
    __shared__ __align__(16) float red[4][32][36];     // 18432 B

    const int n = blockIdx.x;
    const int t = threadIdx.x;
    const int c = t & 31;
    const int g = t >> 5;     // 0..7
    const int wv = t >> 6;    // 0..3

    // ---- stage 9 source pixels (544 ch each), coalesced float4 ----
    for (int idx = t; idx < 9 * 136; idx += 256) {
        const int s  = idx / 136;
        const int e4 = idx - s * 136;
        int cell = n * 9 + s;
        const int b  = cell / 441; cell -= b * 441;
        const int kh = cell / 147; cell -= kh * 147;
        const int kw = cell / 49;  cell -= kw * 49;
        const int i  = cell / 7;
        const int j  = cell - i * 7;
        const float4* src = reinterpret_cast<const float4*>(
            x + (size_t)(((b * 16 + 2 * i + kh) * 16) + 2 * j + kw) * 544);
        reinterpret_cast<float4*>(sbuf + s * 544)[e4] = src[e4];
    }
    __syncthreads();
    // activation slots in place: f = a / (a + EPS)   (strided: covers all 288)
    for (int idx = t; idx < 288; idx += 256) {
        float* ap = sbuf + (idx >> 5) * 544 + 512 + (idx & 31);
        const float a = *ap;
        *ap = a / (a + EPS);
    }
    __syncthreads();

    const float bu_c = bu[c];
    const float ba_c = ba[c];

    float iv[16], dd[16];     // 0.5/sigma^2 and -2*mu*iv
    float lapBase = 0.0f;     // log a_out - sumHalfLog - 8 ln2pi - sum(mu^2 iv)
    #pragma unroll
    for (int p = 0; p < 16; ++p) { iv[p] = 0.0f; dd[p] = 0.0f; }

    #pragma unroll
    for (int it = 0; it < 3; ++it) {
        float pS0 = 0.0f, pS1[16], pS2[16];
        #pragma unroll
        for (int p = 0; p < 16; ++p) { pS1[p] = 0.0f; pS2[p] = 0.0f; }

        #pragma unroll 3
        for (int j = 0; j < 9; ++j) {
            const float* xb = sbuf + j * 544;

            float v[4][16], ff[4];
            #pragma unroll
            for (int u = 0; u < 4; ++u) {
                const int m = g + 8 * u;                 // in-pixel capsule index
                const float* xp = xb + m * 16;
                const float* wp = w + ((size_t)((j << 5) + m) * 32 + c) * 16;
                float xa[16], wf[16];
                #pragma unroll
                for (int q = 0; q < 4; ++q) {
                    float4 tx = reinterpret_cast<const float4*>(xp)[q];
                    float4 tw = reinterpret_cast<const float4*>(wp)[q];
                    xa[4*q] = tx.x; xa[4*q+1] = tx.y; xa[4*q+2] = tx.z; xa[4*q+3] = tx.w;
                    wf[4*q] = tw.x; wf[4*q+1] = tw.y; wf[4*q+2] = tw.z; wf[4*q+3] = tw.w;
                }
                #pragma unroll
                for (int p = 0; p < 4; ++p) {
                    #pragma unroll
                    for (int r = 0; r < 4; ++r) {
                        v[u][p*4+r] = fmaf(xa[p*4+3], wf[12+r],
                                      fmaf(xa[p*4+2], wf[8+r],
                                      fmaf(xa[p*4+1], wf[4+r], xa[p*4+0] * wf[r])));
                    }
                }
                ff[u] = xb[512 + m];
            }

            float rho[4];
            if (it == 0) {
                #pragma unroll
                for (int u = 0; u < 4; ++u) rho[u] = ff[u] * 0.03125f;  // r = 1/32
            } else {
                // lap = lapBase - sum_p (iv*v + dd)*v   (mu^2 term folded into lapBase)
                float e[4], z[4];
                #pragma unroll
                for (int u = 0; u < 4; ++u) {
                    float sA = 0.0f, sB = 0.0f;
                    #pragma unroll
                    for (int p = 0; p < 16; p += 2) {
                        sA = fmaf(fmaf(iv[p],   v[u][p],   dd[p]),   v[u][p],   sA);
                        sB = fmaf(fmaf(iv[p+1], v[u][p+1], dd[p+1]), v[u][p+1], sB);
                    }
                    // no max-subtraction: exp argument well inside f32 range for this data
                    e[u] = __expf(lapBase - (sA + sB));
                    z[u] = e[u];
                }
                redsum4(z[0], z[1], z[2], z[3]);
                #pragma unroll
                for (int u = 0; u < 4; ++u)
                    rho[u] = e[u] * __fdividef(ff[u], z[u]);  // sum_c softmax = 1
            }

            pS0 += (rho[0] + rho[1]) + (rho[2] + rho[3]);
            #pragma unroll
            for (int p = 0; p < 16; ++p) {
                #pragma unroll
                for (int u = 0; u < 4; ++u) {
                    const float rv = rho[u] * v[u][p];
                    pS1[p] += rv;
                    pS2[p] = fmaf(rv, v[u][p], pS2[p]);
                }
            }
        }

        // ---- reduce over 8 g-groups: wave-internal pair combine, then LDS over 4 waves ----
        pS0 += __shfl_xor(pS0, 32);
        #pragma unroll
        for (int p = 0; p < 16; ++p) {
            pS1[p] += __shfl_xor(pS1[p], 32);
            pS2[p] += __shfl_xor(pS2[p], 32);
        }
        if ((t & 32) == 0) {
            float* rp = &red[wv][c][0];
            #pragma unroll
            for (int q = 0; q < 4; ++q) {
                reinterpret_cast<float4*>(rp)[q] =
                    make_float4(pS1[4*q], pS1[4*q+1], pS1[4*q+2], pS1[4*q+3]);
                reinterpret_cast<float4*>(rp + 16)[q] =
                    make_float4(pS2[4*q], pS2[4*q+1], pS2[4*q+2], pS2[4*q+3]);
            }
            rp[32] = pS0;
        }
        __syncthreads();
        float S0 = 0.0f, S1[16], S2[16];
        #pragma unroll
        for (int p = 0; p < 16; ++p) { S1[p] = 0.0f; S2[p] = 0.0f; }
        #pragma unroll
        for (int kk = 0; kk < 4; ++kk) {
            const float* rp = &red[kk][c][0];
            #pragma unroll
            for (int q = 0; q < 4; ++q) {
                const float4 t1 = reinterpret_cast<const float4*>(rp)[q];
                const float4 t2 = reinterpret_cast<const float4*>(rp + 16)[q];
                S1[4*q]   += t1.x; S1[4*q+1] += t1.y; S1[4*q+2] += t1.z; S1[4*q+3] += t1.w;
                S2[4*q]   += t2.x; S2[4*q+1] += t2.y; S2[4*q+2] += t2.z; S2[4*q+3] += t2.w;
            }
            S0 += rp[32];
        }
        __syncthreads();   // red reused next iteration

        // ---- m-step closure ----
        const float inv = 1.0f / (S0 + EPS);
        float sumHalfLog = 0.0f;
        if (it < 2) {
            float Cq = 0.0f;
            #pragma unroll
            for (int p = 0; p < 16; ++p) {
                const float m_ = S1[p] * inv;
                const float sg = (S2[p] - 2.0f * m_ * S1[p] + m_ * m_ * S0) * inv + EPS;
                const float ivp = 0.5f / sg;
                iv[p] = ivp;
                dd[p] = -2.0f * m_ * ivp;
                Cq = fmaf(m_ * m_, ivp, Cq);
                sumHalfLog += 0.5f * __logf(sg);
            }
            const float cost = (16.0f * bu_c + sumHalfLog) * S0;
            const float itc = (it == 0) ? 5.0e-4f : 9.75e-4f;
            const float a_out_c = 1.0f / (1.0f + __expf(-(itc * (ba_c - cost))));
            lapBase = __logf(a_out_c) - sumHalfLog - 8.0f * LN_2PI - Cq;
        } else {
            float mu[16];
            #pragma unroll
            for (int p = 0; p < 16; ++p) {
                const float m_ = S1[p] * inv;
                const float sg = (S2[p] - 2.0f * m_ * S1[p] + m_ * m_ * S0) * inv + EPS;
                mu[p] = m_;
                sumHalfLog += 0.5f * __logf(sg);
            }
            const float cost = (16.0f * bu_c + sumHalfLog) * S0;
            const float a_out_c = 1.0f / (1.0f + __expf(-(1.42625e-3f * (ba_c - cost))));
            if (g == 0) {
                float* po = out + (size_t)n * 544 + c * 16;
                #pragma unroll
                for (int q = 0; q < 4; ++q) {
                    reinterpret_cast<float4*>(po)[q] =
                        make_float4(mu[4*q], mu[4*q+1], mu[4*q+2], mu[4*q+3]);
                }
                out[(size_t)n * 544 + 512 + c] = a_out_c;
            }
        }
    }
}

extern "C" void kernel_launch(void* const* d_in, const int* in_sizes, int n_in,
                              void* d_out, int out_size, void* d_ws, size_t ws_size,
                              hipStream_t stream) {
    const float* x  = (const float*)d_in[0];   // (8,16,16,544) f32
    const float* w  = (const float*)d_in[1];   // (1,288,32,4,4) f32
    const float* bu = (const float*)d_in[2];   // (32,) f32
    const float* ba = (const float*)d_in[3];   // (32,) f32
    float* out = (float*)d_out;                // (8,7,7,544) f32
    convcaps_em_kernel<<<392, 256, 0, stream>>>(x, w, bu, ba, out);
}